// Round 4
// baseline (92.476 us; speedup 1.0000x reference)
//
#include <hip/hip_runtime.h>

typedef __attribute__((ext_vector_type(8))) short bf16x8;
typedef __attribute__((ext_vector_type(4))) float f32x4;
typedef const __attribute__((address_space(1))) void GV;
typedef __attribute__((address_space(3))) void LV;

namespace {
constexpr int NB=8, N1=4096, N2=1024, F1=128, F2=256, H1=256, H2=256;
constexpr int TM=64;
constexpr float SLOPE=0.2f, EPSD=1e-10f;
constexpr int WS_XYZ = 0;                  // 8*1024*16 = 131072 B
constexpr int WS_W1  = 131072;             // 12 chunks * 16384
constexpr int WS_W2  = 327680;             // 8 chunks * 16384
}

__device__ __forceinline__ unsigned short f2bf(float f){
  union{float f; unsigned u;} v; v.f=f;
  unsigned r = v.u + 0x7FFFu + ((v.u>>16)&1u);   // RNE
  return (unsigned short)(r>>16);
}
__device__ __forceinline__ float lrelu(float x){ return x>=0.f? x : SLOPE*x; }
__device__ __forceinline__ void glds16(const void* g, void* l){
  __builtin_amdgcn_global_load_lds((GV*)g,(LV*)l,16,0,0);
}

__global__ __launch_bounds__(256)
void transform_w(const float* __restrict__ W1, const float* __restrict__ W2,
                 const float* __restrict__ xyz2, char* __restrict__ ws)
{
  int id = blockIdx.x * 256 + threadIdx.x;
  if (id < 12288) {                      // W1T: 12 chunks x 256 n x 4 groups
    int c = id >> 10, rem = id & 1023, n = rem >> 2, g = rem & 3;
    const float* src = W1 + (size_t)(32*c + 8*g) * 256 + n;
    unsigned u[4];
    #pragma unroll
    for (int p = 0; p < 4; ++p) {
      unsigned short lo = f2bf(src[(2*p)*256]);
      unsigned short hi = f2bf(src[(2*p+1)*256]);
      u[p] = (unsigned)lo | ((unsigned)hi << 16);
    }
    *(uint4*)(ws + WS_W1 + c*16384 + (n*4 + (g ^ ((n>>1)&3)))*16) =
        make_uint4(u[0],u[1],u[2],u[3]);
  } else if (id < 20480) {               // W2T: 8 chunks
    id -= 12288;
    int c = id >> 10, rem = id & 1023, n = rem >> 2, g = rem & 3;
    const float* src = W2 + (size_t)(32*c + 8*g) * 256 + n;
    unsigned u[4];
    #pragma unroll
    for (int p = 0; p < 4; ++p) {
      unsigned short lo = f2bf(src[(2*p)*256]);
      unsigned short hi = f2bf(src[(2*p+1)*256]);
      u[p] = (unsigned)lo | ((unsigned)hi << 16);
    }
    *(uint4*)(ws + WS_W2 + c*16384 + (n*4 + (g ^ ((n>>1)&3)))*16) =
        make_uint4(u[0],u[1],u[2],u[3]);
  } else if (id < 28672) {               // xyz2q: (x,y,z,sq)
    id -= 20480;
    int bb = id >> 10, j = id & 1023;
    const float* s = xyz2 + ((size_t)bb*N2 + j)*3;
    float x = s[0], y = s[1], z = s[2];
    *(float4*)(ws + WS_XYZ + ((size_t)bb*1024 + j)*16) =
        make_float4(x, y, z, x*x + y*y + z*z);
  }
}

// 512 threads, 8 waves: 2 blocks/CU -> 4 waves/SIMD
__global__ __launch_bounds__(512, 4)
void fp_mfma(const float* __restrict__ xyz1, const float* __restrict__ p1,
             const float* __restrict__ p2,   const char* __restrict__ ws,
             const float* __restrict__ b1,   const float* __restrict__ b2,
             float* __restrict__ out)
{
  __shared__ __align__(16) char smem[65536];
  __shared__ float s_w[TM][4];
  __shared__ int   s_idx[TM][4];

  char* Xt  = smem;            // [0,24576) X tile / [0,16384) cands / [0,32768) h
  char* Wb0 = smem + 32768;
  char* Wb1 = smem + 49152;

  const int t = threadIdx.x;
  const int b = blockIdx.x & 7;            // batch == XCD
  const int row0 = (blockIdx.x >> 3) * TM;
  const int lane = t & 63;
  const int wv = t >> 6;
  const int lrow = lane & 15, lg = lane >> 4;
  const int mh = wv >> 2, nq = wv & 3;     // wave owns 32m x 64n

  // ============ Phase A: 3-NN, 8 j-slices per row ============
  {
    const float4* x2q = (const float4*)(ws + WS_XYZ + (size_t)b*16384);
    const int row = t >> 3, slice = t & 7;
    const float* x1 = xyz1 + ((size_t)b*N1 + row0 + row)*3;
    const float px = x1[0], py = x1[1], pz = x1[2];
    const float sq1 = px*px + py*py + pz*pz;
    float d0=3.4e38f, d1=3.4e38f, d2=3.4e38f;
    int i0=0, i1=0, i2=0;
    const int j0 = slice*128;
    #pragma unroll 8
    for (int j = j0; j < j0+128; ++j) {
      float4 q = x2q[j];
      float dot = px*q.x + py*q.y + pz*q.z;
      float d = fmaf(-2.f, dot, sq1 + q.w);
      bool c0 = d < d0, c1 = d < d1, c2 = d < d2;
      i2 = c1 ? i1 : (c2 ? j : i2);
      i1 = c0 ? i0 : (c1 ? j : i1);
      i0 = c0 ? j  : i0;
      d2 = __builtin_amdgcn_fmed3f(d, d1, d2);
      d1 = __builtin_amdgcn_fmed3f(d, d0, d1);
      d0 = fminf(d, d0);
    }
    float* cd = (float*)(Xt + t*32);
    cd[0]=d0; cd[1]=d1; cd[2]=d2;
    ((int*)cd)[4]=i0; ((int*)cd)[5]=i1; ((int*)cd)[6]=i2;
  }
  __syncthreads();
  if (t < TM) {                            // merge 8 slice-candidates (j-ascending)
    float d0=3.4e38f,d1=3.4e38f,d2=3.4e38f; int i0=0,i1=0,i2=0;
    for (int p=0;p<8;++p){
      const float* cd = (const float*)(Xt + (t*8 + p)*32);
      for (int c=0;c<3;++c){
        float d = cd[c]; int ii = ((const int*)cd)[4+c];
        if (d < d2) {
          if (d < d1) { d2=d1; i2=i1;
            if (d < d0) { d1=d0; i1=i0; d0=d; i0=ii; } else { d1=d; i1=ii; }
          } else { d2=d; i2=ii; }
        }
      }
    }
    d0=fmaxf(d0,EPSD); d1=fmaxf(d1,EPSD); d2=fmaxf(d2,EPSD);
    float w0=1.f/d0, w1=1.f/d1, w2=1.f/d2, inv=1.f/(w0+w1+w2);
    s_w[t][0]=w0*inv; s_w[t][1]=w1*inv; s_w[t][2]=w2*inv;
    s_idx[t][0]=i0; s_idx[t][1]=i1; s_idx[t][2]=i2;
  }
  __syncthreads();

  // ============ Phase B ============
  const int rr = t >> 3, qq = t & 7;       // X build: 8 threads/row, 8 k each
  const float w0_=s_w[rr][0], w1_=s_w[rr][1], w2_=s_w[rr][2];
  const int g0=s_idx[rr][0], g1=s_idx[rr][1], g2=s_idx[rr][2];
  const char* wsW1 = ws + WS_W1;
  const char* wsW2 = ws + WS_W2;
  const float* p2b = p2 + (size_t)b*N2*F2;
  const float* p1r = p1 + ((size_t)b*N1 + row0 + rr)*F1;
  const int r7 = rr & 7;

  auto buildXt = [&](int kcg, int kcl) {   // one 64-k chunk of X
    float v[8];
    const int k0 = kcg*64 + qq*8;
    if (kcg < 4) {
      const float4* q0 = (const float4*)(p2b + (size_t)g0*F2 + k0);
      const float4* q1 = (const float4*)(p2b + (size_t)g1*F2 + k0);
      const float4* q2 = (const float4*)(p2b + (size_t)g2*F2 + k0);
      #pragma unroll
      for (int p = 0; p < 2; ++p) {
        float4 a0 = q0[p], a1 = q1[p], a2 = q2[p];
        v[4*p+0] = fmaf(w2_, a2.x, fmaf(w1_, a1.x, w0_*a0.x));
        v[4*p+1] = fmaf(w2_, a2.y, fmaf(w1_, a1.y, w0_*a0.y));
        v[4*p+2] = fmaf(w2_, a2.z, fmaf(w1_, a1.z, w0_*a0.z));
        v[4*p+3] = fmaf(w2_, a2.w, fmaf(w1_, a1.w, w0_*a0.w));
      }
    } else {
      const float4* q = (const float4*)(p1r + (k0 - F2));
      #pragma unroll
      for (int p = 0; p < 2; ++p) {
        float4 a = q[p];
        v[4*p+0]=a.x; v[4*p+1]=a.y; v[4*p+2]=a.z; v[4*p+3]=a.w;
      }
    }
    unsigned u[4];
    #pragma unroll
    for (int p = 0; p < 4; ++p)
      u[p] = (unsigned)f2bf(v[2*p]) | ((unsigned)f2bf(v[2*p+1]) << 16);
    *(uint4*)(Xt + rr*384 + (kcl*8 + (qq ^ r7))*16) = make_uint4(u[0],u[1],u[2],u[3]);
  };
  auto stage = [&](const char* src, char* dst) {   // 16KB, 512 threads x 2
    glds16(src + t*16,        dst + t*16);
    glds16(src + t*16 + 8192, dst + t*16 + 8192);
  };

  f32x4 acc[2][4];
  #pragma unroll
  for (int mt=0;mt<2;++mt)
    #pragma unroll
    for (int nt=0;nt<4;++nt) acc[mt][nt] = (f32x4){0.f,0.f,0.f,0.f};

  // ---- GEMM1: 12 K32 chunks, dbuf W, X in 2 halves ----
  stage(wsW1, Wb0);
  buildXt(0,0); buildXt(1,1); buildXt(2,2);
  __syncthreads();
  #pragma unroll
  for (int s = 0; s < 12; ++s) {
    char* Wcur = (s & 1) ? Wb1 : Wb0;
    char* Wnxt = (s & 1) ? Wb0 : Wb1;
    if (s < 11) stage(wsW1 + (s+1)*16384, Wnxt);
    const int sl = (s >= 6) ? (s - 6) : s;
    const int kcl = sl >> 1, klo = (sl & 1) * 4;
    bf16x8 af[2], bw[4];
    #pragma unroll
    for (int mt=0;mt<2;++mt) {
      const int m = mh*32 + mt*16 + lrow;
      af[mt] = *(const bf16x8*)(Xt + m*384 + (kcl*8 + ((klo + lg) ^ (m&7)))*16);
    }
    #pragma unroll
    for (int nt=0;nt<4;++nt) {
      const int n = nq*64 + nt*16 + lrow;
      bw[nt] = *(const bf16x8*)(Wcur + (n*4 + (lg ^ ((n>>1)&3)))*16);
    }
    #pragma unroll
    for (int mt=0;mt<2;++mt)
      #pragma unroll
      for (int nt=0;nt<4;++nt)
        acc[mt][nt] = __builtin_amdgcn_mfma_f32_16x16x32_bf16(af[mt], bw[nt], acc[mt][nt], 0,0,0);
    __syncthreads();
    if (s == 5) {
      buildXt(3,0); buildXt(4,1); buildXt(5,2);
      __syncthreads();
    }
  }

  // ---- h = lrelu(acc+b1) -> LDS [64m][256k] bf16 swizzled ----
  stage(wsW2, Wb0);
  {
    float bb[4];
    #pragma unroll
    for (int nt=0;nt<4;++nt) bb[nt] = b1[nq*64 + nt*16 + lrow];
    #pragma unroll
    for (int mt=0;mt<2;++mt)
      #pragma unroll
      for (int rg=0;rg<4;++rg) {
        const int row = mh*32 + mt*16 + lg*4 + rg;
        const int rb = row*512, rw7 = row & 7;
        #pragma unroll
        for (int nt=0;nt<4;++nt) {
          const int col = nq*64 + nt*16 + lrow;
          unsigned short hv = f2bf(lrelu(acc[mt][nt][rg] + bb[nt]));
          *(short*)(smem + rb + (((col>>3) ^ rw7)<<4) + ((lrow&7)*2)) = (short)hv;
        }
      }
  }
  __syncthreads();

  // ---- GEMM2: 8 K32 chunks, dbuf ----
  f32x4 acc2[2][4];
  #pragma unroll
  for (int mt=0;mt<2;++mt)
    #pragma unroll
    for (int nt=0;nt<4;++nt) acc2[mt][nt] = (f32x4){0.f,0.f,0.f,0.f};
  #pragma unroll
  for (int s = 0; s < 8; ++s) {
    char* Wcur = (s & 1) ? Wb1 : Wb0;
    char* Wnxt = (s & 1) ? Wb0 : Wb1;
    if (s < 7) stage(wsW2 + (s+1)*16384, Wnxt);
    bf16x8 af[2], bw[4];
    #pragma unroll
    for (int mt=0;mt<2;++mt) {
      const int m = mh*32 + mt*16 + lrow;
      af[mt] = *(const bf16x8*)(smem + m*512 + (((s*4 + lg) ^ (m&7)))*16);
    }
    #pragma unroll
    for (int nt=0;nt<4;++nt) {
      const int n = nq*64 + nt*16 + lrow;
      bw[nt] = *(const bf16x8*)(Wcur + (n*4 + (lg ^ ((n>>1)&3)))*16);
    }
    #pragma unroll
    for (int mt=0;mt<2;++mt)
      #pragma unroll
      for (int nt=0;nt<4;++nt)
        acc2[mt][nt] = __builtin_amdgcn_mfma_f32_16x16x32_bf16(af[mt], bw[nt], acc2[mt][nt], 0,0,0);
    __syncthreads();
  }

  // ---- epilogue ----
  {
    float bb[4];
    #pragma unroll
    for (int nt=0;nt<4;++nt) bb[nt] = b2[nq*64 + nt*16 + lrow];
    float* ob = out + ((size_t)b*N1 + row0) * H2;
    #pragma unroll
    for (int mt=0;mt<2;++mt)
      #pragma unroll
      for (int rg=0;rg<4;++rg) {
        const int row = mh*32 + mt*16 + lg*4 + rg;
        #pragma unroll
        for (int nt=0;nt<4;++nt) {
          const int col = nq*64 + nt*16 + lrow;
          ob[(size_t)row*H2 + col] = lrelu(acc2[mt][nt][rg] + bb[nt]);
        }
      }
  }
}

extern "C" void kernel_launch(void* const* d_in, const int* in_sizes, int n_in,
                              void* d_out, int out_size, void* d_ws, size_t ws_size,
                              hipStream_t stream) {
  const float* xyz1    = (const float*)d_in[0];
  const float* xyz2    = (const float*)d_in[1];
  const float* points1 = (const float*)d_in[2];
  const float* points2 = (const float*)d_in[3];
  const float* W1      = (const float*)d_in[4];
  const float* b1      = (const float*)d_in[5];
  const float* W2      = (const float*)d_in[6];
  const float* b2      = (const float*)d_in[7];
  float* out = (float*)d_out;

  hipLaunchKernelGGL(transform_w, dim3(112), dim3(256), 0, stream,
                     W1, W2, xyz2, (char*)d_ws);
  hipLaunchKernelGGL(fp_mfma, dim3(NB * (N1 / TM)), dim3(512), 0, stream,
                     xyz1, points1, points2, (const char*)d_ws, b1, b2, out);
}

// Round 5
// 55.902 us; speedup vs baseline: 1.6543x; 1.6543x over previous
//
#include <hip/hip_runtime.h>

typedef __attribute__((ext_vector_type(8))) short bf16x8;
typedef __attribute__((ext_vector_type(4))) float f32x4;

namespace {
constexpr int NB=8, N1=4096, N2=1024, F1=128, F2=256, H2=256;
constexpr int TM=64;
constexpr float SLOPE=0.2f, EPSD=1e-10f;
constexpr int WS_XYZ=0, WS_W1=131072, WS_W2=327680;
constexpr int XT_STRIDE=400;   // 384B row + 16B pad -> rows rotate 4 banks
constexpr int H_STRIDE=528;    // 512B row + 16B pad
}

__device__ __forceinline__ unsigned short f2bf(float f){
  union{float f; unsigned u;} v; v.f=f;
  unsigned r = v.u + 0x7FFFu + ((v.u>>16)&1u);   // RNE
  return (unsigned short)(r>>16);
}
__device__ __forceinline__ float lrelu(float x){ return x>=0.f? x : SLOPE*x; }

// W1/W2 -> bf16 transposed, MFMA-fragment-linear: frag id = s*16 + nq*4 + nt,
// frag content lane*16B = 8 bf16 along k for (n = nq*64+nt*16+(lane&15),
// k0 = s*32+(lane>>4)*8). xyz2 -> (x,y,z,|.|^2).
__global__ __launch_bounds__(256)
void transform_w(const float* __restrict__ W1, const float* __restrict__ W2,
                 const float* __restrict__ xyz2, char* __restrict__ ws)
{
  int id = blockIdx.x*256 + threadIdx.x;
  if (id < 12288) {                       // W1T: 192 frags x 64 lanes
    int frag = id >> 6, ln = id & 63;
    int n = (((frag>>2)&3)*64) + ((frag&3)*16) + (ln & 15);
    int k0 = (frag>>4)*32 + (ln>>4)*8;
    const float* src = W1 + (size_t)k0*256 + n;
    unsigned u[4];
    #pragma unroll
    for (int p=0;p<4;++p)
      u[p] = (unsigned)f2bf(src[(2*p)*256]) | ((unsigned)f2bf(src[(2*p+1)*256])<<16);
    *(uint4*)(ws + WS_W1 + frag*1024 + ln*16) = make_uint4(u[0],u[1],u[2],u[3]);
  } else if (id < 20480) {                // W2T: 128 frags
    id -= 12288;
    int frag = id >> 6, ln = id & 63;
    int n = (((frag>>2)&3)*64) + ((frag&3)*16) + (ln & 15);
    int k0 = (frag>>4)*32 + (ln>>4)*8;
    const float* src = W2 + (size_t)k0*256 + n;
    unsigned u[4];
    #pragma unroll
    for (int p=0;p<4;++p)
      u[p] = (unsigned)f2bf(src[(2*p)*256]) | ((unsigned)f2bf(src[(2*p+1)*256])<<16);
    *(uint4*)(ws + WS_W2 + frag*1024 + ln*16) = make_uint4(u[0],u[1],u[2],u[3]);
  } else if (id < 28672) {                // xyz2q
    id -= 20480;
    int bb = id >> 10, j = id & 1023;
    const float* sp = xyz2 + ((size_t)bb*N2 + j)*3;
    float x=sp[0], y=sp[1], z=sp[2];
    *(float4*)(ws + WS_XYZ + ((size_t)bb*1024 + j)*16) =
        make_float4(x,y,z,x*x+y*y+z*z);
  }
}

__global__ __launch_bounds__(256, 2)
void fp_mfma(const float* __restrict__ xyz1, const float* __restrict__ p1,
             const float* __restrict__ p2,   const char* __restrict__ ws,
             const float* __restrict__ b1,   const float* __restrict__ b2,
             float* __restrict__ out)
{
  __shared__ __align__(16) char smem[33792];   // cand 8K -> Xt 25.6K -> h 33.8K
  __shared__ float s_w[TM][4];
  __shared__ int   s_idx[TM][4];

  const int t = threadIdx.x;
  const int b = blockIdx.x & 7;                // batch == XCD
  const int row0 = (blockIdx.x >> 3) * TM;
  const int lane = t & 63, wv = t >> 6;
  const int lrow = lane & 15, lg = lane >> 4;
  const int nq = wv;                           // wave owns n-quadrant, all 64 m

  // ===== Phase A: 3-NN. wave = j-slice (uniform addr -> s_load), lane = row =====
  {
    const float4* x2q = (const float4*)(ws + WS_XYZ + (size_t)b*16384);
    const float* x1 = xyz1 + ((size_t)b*N1 + row0 + lane)*3;
    const float px=x1[0], py=x1[1], pz=x1[2];
    const float sq1 = px*px + py*py + pz*pz;
    float d0=3.4e38f, d1=3.4e38f, d2=3.4e38f;
    int i0=0, i1=0, i2=0;
    const int j0 = wv*256;
    #pragma unroll 4
    for (int j = j0; j < j0+256; ++j) {
      float4 q = x2q[j];
      float dot = px*q.x + py*q.y + pz*q.z;
      float d = fmaf(-2.f, dot, sq1 + q.w);
      bool c0 = d < d0, c1 = d < d1, c2 = d < d2;
      i2 = c1 ? i1 : (c2 ? j : i2);
      i1 = c0 ? i0 : (c1 ? j : i1);
      i0 = c0 ? j  : i0;
      d2 = __builtin_amdgcn_fmed3f(d, d1, d2);
      d1 = __builtin_amdgcn_fmed3f(d, d0, d1);
      d0 = fminf(d, d0);
    }
    float* cd = (float*)smem + t*8;
    cd[0]=d0; cd[1]=d1; cd[2]=d2;
    ((int*)cd)[4]=i0; ((int*)cd)[5]=i1; ((int*)cd)[6]=i2;
  }
  __syncthreads();
  if (t < TM) {                                // ascending-slice merge (tie = ref)
    float d0=3.4e38f,d1=3.4e38f,d2=3.4e38f; int i0=0,i1=0,i2=0;
    for (int p=0;p<4;++p){
      const float* cd = (const float*)smem + (p*64 + t)*8;
      for (int c=0;c<3;++c){
        float d = cd[c]; int ii = ((const int*)cd)[4+c];
        if (d < d2) {
          if (d < d1) { d2=d1; i2=i1;
            if (d < d0) { d1=d0; i1=i0; d0=d; i0=ii; } else { d1=d; i1=ii; }
          } else { d2=d; i2=ii; }
        }
      }
    }
    d0=fmaxf(d0,EPSD); d1=fmaxf(d1,EPSD); d2=fmaxf(d2,EPSD);
    float w0=1.f/d0, w1=1.f/d1, w2=1.f/d2, inv=1.f/(w0+w1+w2);
    s_w[t][0]=w0*inv; s_w[t][1]=w1*inv; s_w[t][2]=w2*inv;
    s_idx[t][0]=i0; s_idx[t][1]=i1; s_idx[t][2]=i2;
  }
  __syncthreads();

  // ===== Phase B =====
  const int rr = t >> 2, qq = t & 3;           // build: 4 thr/row, 16 k each
  const float w0_=s_w[rr][0], w1_=s_w[rr][1], w2_=s_w[rr][2];
  const int g0=s_idx[rr][0], g1=s_idx[rr][1], g2=s_idx[rr][2];
  const char* wsW1 = ws + WS_W1;
  const char* wsW2 = ws + WS_W2;
  const float* p2b = p2 + (size_t)b*N2*F2;
  const float* p1r = p1 + ((size_t)b*N1 + row0 + rr)*F1;
  char* Xt = smem;
  __syncthreads();                             // cand region now reusable as Xt

  auto issueG = [&](int kcg, float4* g){       // gather 16 floats x 3 neighbors
    const int k0 = kcg*64 + qq*16;
    const float4* q0 = (const float4*)(p2b + (size_t)g0*F2 + k0);
    const float4* q1 = (const float4*)(p2b + (size_t)g1*F2 + k0);
    const float4* q2 = (const float4*)(p2b + (size_t)g2*F2 + k0);
    #pragma unroll
    for (int p=0;p<4;++p){ g[p]=q0[p]; g[4+p]=q1[p]; g[8+p]=q2[p]; }
  };
  auto issueP1 = [&](int kcg, float4* g){      // points1 passthrough
    const float4* q = (const float4*)(p1r + (kcg*64 + qq*16 - F2));
    #pragma unroll
    for (int p=0;p<4;++p) g[p]=q[p];
  };
  auto writeG = [&](int kcl, const float4* g){ // interp -> bf16 -> 2 slots
    float v[16];
    #pragma unroll
    for (int p=0;p<4;++p){
      v[4*p+0] = fmaf(w2_, g[8+p].x, fmaf(w1_, g[4+p].x, w0_*g[p].x));
      v[4*p+1] = fmaf(w2_, g[8+p].y, fmaf(w1_, g[4+p].y, w0_*g[p].y));
      v[4*p+2] = fmaf(w2_, g[8+p].z, fmaf(w1_, g[4+p].z, w0_*g[p].z));
      v[4*p+3] = fmaf(w2_, g[8+p].w, fmaf(w1_, g[4+p].w, w0_*g[p].w));
    }
    unsigned u[8];
    #pragma unroll
    for (int p=0;p<8;++p)
      u[p] = (unsigned)f2bf(v[2*p]) | ((unsigned)f2bf(v[2*p+1])<<16);
    *(uint4*)(Xt + rr*XT_STRIDE + (kcl*8 + qq*2    )*16) = make_uint4(u[0],u[1],u[2],u[3]);
    *(uint4*)(Xt + rr*XT_STRIDE + (kcl*8 + qq*2 + 1)*16) = make_uint4(u[4],u[5],u[6],u[7]);
  };
  auto writeP1 = [&](int kcl, const float4* g){
    unsigned u[8];
    #pragma unroll
    for (int p=0;p<4;++p){
      u[2*p+0] = (unsigned)f2bf(g[p].x) | ((unsigned)f2bf(g[p].y)<<16);
      u[2*p+1] = (unsigned)f2bf(g[p].z) | ((unsigned)f2bf(g[p].w)<<16);
    }
    *(uint4*)(Xt + rr*XT_STRIDE + (kcl*8 + qq*2    )*16) = make_uint4(u[0],u[1],u[2],u[3]);
    *(uint4*)(Xt + rr*XT_STRIDE + (kcl*8 + qq*2 + 1)*16) = make_uint4(u[4],u[5],u[6],u[7]);
  };
  auto loadW = [&](const char* base, int s, bf16x8* dst){  // coalesced 1KB frags
    #pragma unroll
    for (int nt=0;nt<4;++nt)
      dst[nt] = *(const bf16x8*)(base + ((s*16 + nq*4 + nt)<<10) + lane*16);
  };
  auto gemmStep = [&](int slot4, const bf16x8* bw, f32x4 (&ac)[4][4],
                      const char* Abase, int stride){
    bf16x8 af[4];
    #pragma unroll
    for (int mt=0;mt<4;++mt)
      af[mt] = *(const bf16x8*)(Abase + (mt*16+lrow)*stride + (slot4+lg)*16);
    #pragma unroll
    for (int mt=0;mt<4;++mt)
      #pragma unroll
      for (int nt=0;nt<4;++nt)
        ac[mt][nt] = __builtin_amdgcn_mfma_f32_16x16x32_bf16(af[mt], bw[nt], ac[mt][nt], 0,0,0);
  };

  f32x4 acc[4][4];
  #pragma unroll
  for (int mt=0;mt<4;++mt)
    #pragma unroll
    for (int nt=0;nt<4;++nt) acc[mt][nt] = (f32x4){0.f,0.f,0.f,0.f};

  // ---- GEMM1: X(64x384) @ W1, W from global (reg dbuf), X halves in LDS ----
  float4 gA0[12], gA1[12], gA2[12], gB3[12], gP4[4], gP5[4];
  bf16x8 bwA[4], bwB[4];

  issueG(0,gA0); issueG(1,gA1);
  loadW(wsW1, 0, bwA);
  issueG(2,gA2);
  writeG(0,gA0);
  issueG(3,gB3); issueP1(4,gP4); issueP1(5,gP5);   // half-B burst, hidden under half-A
  writeG(1,gA1); writeG(2,gA2);
  __syncthreads();
  #pragma unroll
  for (int u=0; u<3; ++u) {                    // s = 0..5
    loadW(wsW1, 2*u+1, bwB);
    gemmStep((2*u)*4,   bwA, acc, Xt, XT_STRIDE);
    loadW(wsW1, 2*u+2, bwA);
    gemmStep((2*u+1)*4, bwB, acc, Xt, XT_STRIDE);
  }
  __syncthreads();
  writeG(0,gB3); writeP1(1,gP4); writeP1(2,gP5);   // half B (loads long since done)
  __syncthreads();
  #pragma unroll
  for (int u=0; u<3; ++u) {                    // s = 6..11
    loadW(wsW1, 7+2*u, bwB);
    gemmStep((2*u)*4,   bwA, acc, Xt, XT_STRIDE);
    if (u<2) loadW(wsW1, 8+2*u, bwA);
    else     loadW(wsW2, 0, bwA);              // prefetch W2 chunk 0
    gemmStep((2*u+1)*4, bwB, acc, Xt, XT_STRIDE);
  }
  __syncthreads();                             // Xt dead; h reuses region

  // ---- h = lrelu(acc + b1) -> LDS [64][264 shorts] (stride 528B) ----
  {
    float bb[4];
    #pragma unroll
    for (int nt=0;nt<4;++nt) bb[nt] = b1[nq*64 + nt*16 + lrow];
    #pragma unroll
    for (int mt=0;mt<4;++mt)
      #pragma unroll
      for (int rg=0;rg<4;++rg) {
        const int row = mt*16 + lg*4 + rg;
        #pragma unroll
        for (int nt=0;nt<4;++nt) {
          const int col = nq*64 + nt*16 + lrow;
          *(short*)(smem + row*H_STRIDE + col*2) =
              (short)f2bf(lrelu(acc[mt][nt][rg] + bb[nt]));
        }
      }
  }
  __syncthreads();

  // ---- GEMM2: h(64x256) @ W2, W from global (reg dbuf) ----
  f32x4 acc2[4][4];
  #pragma unroll
  for (int mt=0;mt<4;++mt)
    #pragma unroll
    for (int nt=0;nt<4;++nt) acc2[mt][nt] = (f32x4){0.f,0.f,0.f,0.f};
  #pragma unroll
  for (int u=0; u<4; ++u) {                    // s = 0..7
    loadW(wsW2, 2*u+1, bwB);
    gemmStep((2*u)*4,   bwA, acc2, smem, H_STRIDE);
    if (u<3) loadW(wsW2, 2*u+2, bwA);
    gemmStep((2*u+1)*4, bwB, acc2, smem, H_STRIDE);
  }

  // ---- epilogue ----
  {
    float bb[4];
    #pragma unroll
    for (int nt=0;nt<4;++nt) bb[nt] = b2[nq*64 + nt*16 + lrow];
    float* ob = out + ((size_t)b*N1 + row0) * H2;
    #pragma unroll
    for (int mt=0;mt<4;++mt)
      #pragma unroll
      for (int rg=0;rg<4;++rg) {
        const int row = mt*16 + lg*4 + rg;
        #pragma unroll
        for (int nt=0;nt<4;++nt) {
          const int col = nq*64 + nt*16 + lrow;
          ob[(size_t)row*H2 + col] = lrelu(acc2[mt][nt][rg] + bb[nt]);
        }
      }
  }
}

extern "C" void kernel_launch(void* const* d_in, const int* in_sizes, int n_in,
                              void* d_out, int out_size, void* d_ws, size_t ws_size,
                              hipStream_t stream) {
  const float* xyz1    = (const float*)d_in[0];
  const float* xyz2    = (const float*)d_in[1];
  const float* points1 = (const float*)d_in[2];
  const float* points2 = (const float*)d_in[3];
  const float* W1      = (const float*)d_in[4];
  const float* b1      = (const float*)d_in[5];
  const float* W2      = (const float*)d_in[6];
  const float* b2      = (const float*)d_in[7];
  float* out = (float*)d_out;

  hipLaunchKernelGGL(transform_w, dim3(112), dim3(256), 0, stream,
                     W1, W2, xyz2, (char*)d_ws);
  hipLaunchKernelGGL(fp_mfma, dim3(NB * (N1 / TM)), dim3(256), 0, stream,
                     xyz1, points1, points2, (const char*)d_ws, b1, b2, out);
}